// Round 5
// baseline (1005.495 us; speedup 1.0000x reference)
//
#include <hip/hip_runtime.h>
#include <hip/hip_fp16.h>

static constexpr float BN_EPS = 1e-5f;

__device__ __forceinline__ ushort f2h(float f) {
    return __half_as_ushort(__float2half(f));           // RNE
}
__device__ __forceinline__ float2 h2f2(uint u) {
    __half2 h = *reinterpret_cast<__half2*>(&u);
    return __half22float2(h);
}

// ---------------------------------------------------------------------------
// fp32 -> fp16 bulk convert (vectorized, grid-stride)
// ---------------------------------------------------------------------------
__global__ __launch_bounds__(256) void cvt_f16(
    const float* __restrict__ in, ushort* __restrict__ out, int n4)
{
    int i = blockIdx.x * 256 + threadIdx.x;
    const int stride = gridDim.x * 256;
    for (; i < n4; i += stride) {
        const float4 v = ((const float4*)in)[i];
        ushort4 u;
        u.x = f2h(v.x); u.y = f2h(v.y); u.z = f2h(v.z); u.w = f2h(v.w);
        ((ushort4*)out)[i] = u;
    }
}

// ---------------------------------------------------------------------------
// CSR build, two-pass binned counting sort by dst.
// Pass 0: per-node counts. Pass scan: off[]. Pass A: scatter to coarse
// buckets (dst>>7), dst low bits packed in payload. Pass B: per-bucket block,
// LDS fine heads, bucket-local scatter to final CSR order.
// ---------------------------------------------------------------------------
__global__ __launch_bounds__(256) void count_dst(
    const int* __restrict__ dst, int* __restrict__ cnt, int E)
{
    int i = blockIdx.x * 256 + threadIdx.x;
    const int stride = gridDim.x * 256;
    for (; i < E; i += stride) atomicAdd(&cnt[dst[i]], 1);
}

__device__ inline int wave_incl_scan(int v, int lane)
{
#pragma unroll
    for (int s = 1; s < 64; s <<= 1) {
        const int t = __shfl_up(v, s, 64);
        if (lane >= s) v += t;
    }
    return v;
}

// phase 1: per-block (1024 elems) exclusive scan + block total
__global__ __launch_bounds__(1024) void scan1(
    const int* __restrict__ cnt, int* __restrict__ off, int* __restrict__ bsum, int n)
{
    __shared__ int wsum[16];
    const int tid = threadIdx.x, lane = tid & 63, wid = tid >> 6;
    const int i = blockIdx.x * 1024 + tid;
    const int v = (i < n) ? cnt[i] : 0;
    const int incl = wave_incl_scan(v, lane);
    if (lane == 63) wsum[wid] = incl;
    __syncthreads();
    if (wid == 0) {
        int wv = (lane < 16) ? wsum[lane] : 0;
        wv = wave_incl_scan(wv, lane);
        if (lane < 16) wsum[lane] = wv;
    }
    __syncthreads();
    const int excl = (wid > 0 ? wsum[wid - 1] : 0) + incl - v;
    if (i < n) off[i] = excl;
    if (tid == 1023) bsum[blockIdx.x] = wsum[15];
}

// phase 2: scan the (<=64) block totals with one wave
__global__ __launch_bounds__(64) void scan2(int* __restrict__ bsum, int nb)
{
    const int lane = threadIdx.x;
    const int v = (lane < nb) ? bsum[lane] : 0;
    const int incl = wave_incl_scan(v, lane);
    if (lane < nb) bsum[lane] = incl - v;
}

// phase 3: add block offsets, set off[n]
__global__ __launch_bounds__(1024) void scan3(
    int* __restrict__ off, const int* __restrict__ bsum, int n, int E)
{
    const int i = blockIdx.x * 1024 + threadIdx.x;
    if (i < n) {
        off[i] += bsum[blockIdx.x];
    } else if (i == n) {
        off[n] = E;
    }
}

__global__ __launch_bounds__(256) void init_headA(
    const int* __restrict__ off, int* __restrict__ headA, int NB)
{
    const int b = blockIdx.x * 256 + threadIdx.x;
    if (b < NB) headA[b] = off[b * 128];
}

// Pass A: coarse scatter. payload = {src | (dst&127)<<20, ea-bits}
__global__ __launch_bounds__(256) void fill_coarse(
    const int* __restrict__ src, const int* __restrict__ dst,
    const float* __restrict__ ea, int* __restrict__ headA,
    int2* __restrict__ tmp, int E)
{
    int i = blockIdx.x * 256 + threadIdx.x;
    const int stride = gridDim.x * 256;
    for (; i < E; i += stride) {
        const int d = dst[i];
        const int pos = atomicAdd(&headA[d >> 7], 1);
        tmp[pos] = make_int2(src[i] | ((d & 127) << 20), __float_as_int(ea[i]));
    }
}

// Pass B: per-bucket fine scatter with LDS heads.
__global__ __launch_bounds__(256) void fill_fine(
    const int2* __restrict__ tmp, const int* __restrict__ off,
    int2* __restrict__ edges, int N)
{
    __shared__ int headl[128];
    const int base = blockIdx.x * 128;
    const int nn = min(128, N - base);
    const int tid = threadIdx.x;
    if (tid < nn) headl[tid] = off[base + tid];
    __syncthreads();
    const int lo = off[base];
    const int hi = off[min(base + 128, N)];
    for (int i = lo + tid; i < hi; i += 256) {
        const int2 p = tmp[i];
        const int dl = (p.x >> 20) & 127;
        const int pos = atomicAdd(&headl[dl], 1);
        edges[pos] = make_int2(p.x & 0xFFFFF, p.y);
    }
}

// ---------------------------------------------------------------------------
// GINE aggregation (CSR): 32 lanes per node (4 cols/lane), 2 nodes per wave,
// software-pipelined fp16 row gather.
// acc[node] = res[node] + sum_p relu(xbn[src_p] + a_p*lw + lb)
// ---------------------------------------------------------------------------
template<bool AFF>
__global__ __launch_bounds__(256) void gine_aggr(
    const ushort* __restrict__ xh, const float* __restrict__ xres,
    const int* __restrict__ off, const int2* __restrict__ edges,
    const float* __restrict__ lw, const float* __restrict__ lb,
    const float* __restrict__ sc, const float* __restrict__ sh,
    float* __restrict__ acc, int N)
{
    const int q = threadIdx.x & 31;                 // column quad: cols 4q..4q+3
    const int node = blockIdx.x * 8 + (threadIdx.x >> 5);
    if (node >= N) return;
    const float4 lw4 = ((const float4*)lw)[q];
    const float4 lb4 = ((const float4*)lb)[q];
    float4 sc4, sh4;
    if constexpr (AFF) {
        sc4 = ((const float4*)sc)[q];
        sh4 = ((const float4*)sh)[q];
    }
    float4 s;
    if constexpr (AFF) {
        const uint2 u = ((const uint2*)(xh + (size_t)node * 128))[q];
        const float2 f0 = h2f2(u.x), f1 = h2f2(u.y);
        s.x = fmaf(f0.x, sc4.x, sh4.x);
        s.y = fmaf(f0.y, sc4.y, sh4.y);
        s.z = fmaf(f1.x, sc4.z, sh4.z);
        s.w = fmaf(f1.y, sc4.w, sh4.w);
    } else {
        s = ((const float4*)(xres + (size_t)node * 128))[q];
    }
    int p = off[node];
    const int pend = off[node + 1];
    if (p < pend) {
        int2 e = edges[p];
        uint2 u = ((const uint2*)(xh + (size_t)e.x * 128))[q];
        for (++p; p < pend; ++p) {
            const int2 en = edges[p];
            const uint2 un = ((const uint2*)(xh + (size_t)en.x * 128))[q];
            const float a = __int_as_float(e.y);
            float2 f0 = h2f2(u.x), f1 = h2f2(u.y);
            if constexpr (AFF) {
                f0.x = fmaf(f0.x, sc4.x, sh4.x); f0.y = fmaf(f0.y, sc4.y, sh4.y);
                f1.x = fmaf(f1.x, sc4.z, sh4.z); f1.y = fmaf(f1.y, sc4.w, sh4.w);
            }
            s.x += fmaxf(fmaf(a, lw4.x, lb4.x) + f0.x, 0.f);
            s.y += fmaxf(fmaf(a, lw4.y, lb4.y) + f0.y, 0.f);
            s.z += fmaxf(fmaf(a, lw4.z, lb4.z) + f1.x, 0.f);
            s.w += fmaxf(fmaf(a, lw4.w, lb4.w) + f1.y, 0.f);
            e = en; u = un;
        }
        const float a = __int_as_float(e.y);
        float2 f0 = h2f2(u.x), f1 = h2f2(u.y);
        if constexpr (AFF) {
            f0.x = fmaf(f0.x, sc4.x, sh4.x); f0.y = fmaf(f0.y, sc4.y, sh4.y);
            f1.x = fmaf(f1.x, sc4.z, sh4.z); f1.y = fmaf(f1.y, sc4.w, sh4.w);
        }
        s.x += fmaxf(fmaf(a, lw4.x, lb4.x) + f0.x, 0.f);
        s.y += fmaxf(fmaf(a, lw4.y, lb4.y) + f0.y, 0.f);
        s.z += fmaxf(fmaf(a, lw4.z, lb4.z) + f1.x, 0.f);
        s.w += fmaxf(fmaf(a, lw4.w, lb4.w) + f1.y, 0.f);
    }
    ((float4*)(acc + (size_t)node * 128))[q] = s;
}

// ---------------------------------------------------------------------------
// Fused GEMM + bias + relu + BN-stats epilogue, optional input BN-affine.
// ---------------------------------------------------------------------------
template<int K, int KS, int M, int BY, int TR, bool A1H, bool AFF1, bool AFF2, bool YH>
__global__ __launch_bounds__((M / 4) * BY) void gemm_rs(
    const void* __restrict__ A1v, const float* __restrict__ A2,
    const float* __restrict__ sc1, const float* __restrict__ sh1,
    const float* __restrict__ sc2, const float* __restrict__ sh2,
    const float* __restrict__ W, const float* __restrict__ bias,
    void* __restrict__ Yv, float* __restrict__ sum, float* __restrict__ sq, int N)
{
    constexpr int BX = M / 4;
    constexpr int NT = BX * BY;
    constexpr int R  = BY * TR;        // 64 rows per block
    constexpr int KC = 32;
    constexpr int AST = R + 4;
    __shared__ float Ws[KC * M];
    __shared__ float As[KC * AST];
    __shared__ float Red[2][BY][M];
    const int tx = threadIdx.x, ty = threadIdx.y;
    const int tid = ty * BX + tx;
    const int row0 = blockIdx.x * R;

    float acc[TR][4];
#pragma unroll
    for (int r = 0; r < TR; ++r) { acc[r][0] = acc[r][1] = acc[r][2] = acc[r][3] = 0.f; }

    for (int kc = 0; kc < K; kc += KC) {
        __syncthreads();
        for (int i = tid; i < KC * M / 4; i += NT)
            ((float4*)Ws)[i] = ((const float4*)(W + (size_t)kc * M))[i];
        for (int i = tid; i < R * KC / 4; i += NT) {
            const int r  = i / (KC / 4);
            const int k4 = i % (KC / 4);
            int row = row0 + r; if (row >= N) row = N - 1;   // clamp (stats/stores guarded)
            const int kg = kc + k4 * 4;
            float4 v;
            bool use2 = false;
            if constexpr (KS < K) use2 = (kg >= KS);
            if (use2) {
                const int kl = kg - KS;
                v = *(const float4*)(A2 + (size_t)row * (K - KS) + kl);
                if constexpr (AFF2) {
                    const float4 c = *(const float4*)(sc2 + kl);
                    const float4 d = *(const float4*)(sh2 + kl);
                    v.x = fmaf(v.x, c.x, d.x); v.y = fmaf(v.y, c.y, d.y);
                    v.z = fmaf(v.z, c.z, d.z); v.w = fmaf(v.w, c.w, d.w);
                }
            } else {
                if constexpr (A1H) {
                    const uint2 u = *(const uint2*)((const ushort*)A1v + (size_t)row * KS + kg);
                    const float2 f0 = h2f2(u.x), f1 = h2f2(u.y);
                    v.x = f0.x; v.y = f0.y; v.z = f1.x; v.w = f1.y;
                } else {
                    v = *(const float4*)((const float*)A1v + (size_t)row * KS + kg);
                }
                if constexpr (AFF1) {
                    const float4 c = *(const float4*)(sc1 + kg);
                    const float4 d = *(const float4*)(sh1 + kg);
                    v.x = fmaf(v.x, c.x, d.x); v.y = fmaf(v.y, c.y, d.y);
                    v.z = fmaf(v.z, c.z, d.z); v.w = fmaf(v.w, c.w, d.w);
                }
            }
            As[(k4 * 4 + 0) * AST + r] = v.x;
            As[(k4 * 4 + 1) * AST + r] = v.y;
            As[(k4 * 4 + 2) * AST + r] = v.z;
            As[(k4 * 4 + 3) * AST + r] = v.w;
        }
        __syncthreads();
#pragma unroll 8
        for (int kk = 0; kk < KC; ++kk) {
            const float4 w4 = *(const float4*)&Ws[kk * M + tx * 4];
            float a[TR];
            if constexpr (TR % 4 == 0) {
#pragma unroll
                for (int q = 0; q < TR / 4; ++q) {
                    const float4 av = *(const float4*)&As[kk * AST + ty * TR + q * 4];
                    a[q * 4 + 0] = av.x; a[q * 4 + 1] = av.y;
                    a[q * 4 + 2] = av.z; a[q * 4 + 3] = av.w;
                }
            } else {
#pragma unroll
                for (int r = 0; r < TR; ++r) a[r] = As[kk * AST + ty * TR + r];
            }
#pragma unroll
            for (int r = 0; r < TR; ++r) {
                acc[r][0] = fmaf(a[r], w4.x, acc[r][0]);
                acc[r][1] = fmaf(a[r], w4.y, acc[r][1]);
                acc[r][2] = fmaf(a[r], w4.z, acc[r][2]);
                acc[r][3] = fmaf(a[r], w4.w, acc[r][3]);
            }
        }
    }
    // epilogue: bias + relu + store + per-block column stats
    const float4 b4 = ((const float4*)bias)[tx];
    float s4[4] = {0.f, 0.f, 0.f, 0.f}, q4[4] = {0.f, 0.f, 0.f, 0.f};
#pragma unroll
    for (int r = 0; r < TR; ++r) {
        const int row = row0 + ty * TR + r;
        if (row < N) {
            const float o0 = fmaxf(acc[r][0] + b4.x, 0.f);
            const float o1 = fmaxf(acc[r][1] + b4.y, 0.f);
            const float o2 = fmaxf(acc[r][2] + b4.z, 0.f);
            const float o3 = fmaxf(acc[r][3] + b4.w, 0.f);
            if constexpr (YH) {
                ushort4 u;
                u.x = f2h(o0); u.y = f2h(o1); u.z = f2h(o2); u.w = f2h(o3);
                ((ushort4*)((ushort*)Yv + (size_t)row * M))[tx] = u;
            } else {
                float4 o; o.x = o0; o.y = o1; o.z = o2; o.w = o3;
                ((float4*)((float*)Yv + (size_t)row * M))[tx] = o;
            }
            s4[0] += o0; q4[0] = fmaf(o0, o0, q4[0]);
            s4[1] += o1; q4[1] = fmaf(o1, o1, q4[1]);
            s4[2] += o2; q4[2] = fmaf(o2, o2, q4[2]);
            s4[3] += o3; q4[3] = fmaf(o3, o3, q4[3]);
        }
    }
#pragma unroll
    for (int j = 0; j < 4; ++j) {
        Red[0][ty][tx * 4 + j] = s4[j];
        Red[1][ty][tx * 4 + j] = q4[j];
    }
    __syncthreads();
    if (tid < M) {
        float S = 0.f, Q = 0.f;
#pragma unroll 4
        for (int t = 0; t < BY; ++t) { S += Red[0][t][tid]; Q += Red[1][t][tid]; }
        unsafeAtomicAdd(&sum[tid], S);
        unsafeAtomicAdd(&sq[tid], Q);
    }
}

template<int M>
__global__ void bn_finalize(const float* __restrict__ sum, const float* __restrict__ sq,
                            const float* __restrict__ g, const float* __restrict__ be,
                            float* __restrict__ scale, float* __restrict__ shift, float invN)
{
    const int i = threadIdx.x;
    if (i < M) {
        const float m = sum[i] * invN;
        const float v = sq[i] * invN - m * m;
        const float sc = g[i] * rsqrtf(v + BN_EPS);
        scale[i] = sc;
        shift[i] = be[i] - m * sc;
    }
}

__global__ __launch_bounds__(256) void bn_apply_final(
    const float* __restrict__ Y16, const float* __restrict__ scale,
    const float* __restrict__ shift, float* __restrict__ out, int total)
{
    for (int i = blockIdx.x * 256 + threadIdx.x; i < total; i += gridDim.x * 256) {
        const int n = i / 10;
        const int c = i - n * 10;
        out[i] = fmaf(Y16[(size_t)n * 16 + c], scale[c], shift[c]);
    }
}

// pad w5 [96,10] -> [96,16], b5 [10] -> [16]
__global__ __launch_bounds__(256) void pad_w5(
    const float* __restrict__ w5, const float* __restrict__ b5,
    float* __restrict__ w5p, float* __restrict__ b5p)
{
    const int i = blockIdx.x * 256 + threadIdx.x;
    if (i < 96 * 16) {
        const int k = i >> 4, c = i & 15;
        w5p[i] = (c < 10) ? w5[k * 10 + c] : 0.f;
    } else if (i < 96 * 16 + 16) {
        const int c = i - 96 * 16;
        b5p[c] = (c < 10) ? b5[c] : 0.f;
    }
}

// ---------------------------------------------------------------------------
extern "C" void kernel_launch(void* const* d_in, const int* in_sizes, int n_in,
                              void* d_out, int out_size, void* d_ws, size_t ws_size,
                              hipStream_t stream)
{
    const float* x   = (const float*)d_in[0];
    const float* ea  = (const float*)d_in[1];
    const int*   ei  = (const int*)d_in[2];
    const float* lw  = (const float*)d_in[3];
    const float* lb  = (const float*)d_in[4];
    const float* w1  = (const float*)d_in[5];
    const float* b1  = (const float*)d_in[6];
    const float* g1  = (const float*)d_in[7];
    const float* be1 = (const float*)d_in[8];
    const float* w2  = (const float*)d_in[9];
    const float* b2  = (const float*)d_in[10];
    const float* g2  = (const float*)d_in[11];
    const float* be2 = (const float*)d_in[12];
    const float* w3  = (const float*)d_in[13];
    const float* b3  = (const float*)d_in[14];
    const float* g3  = (const float*)d_in[15];
    const float* be3 = (const float*)d_in[16];
    const float* w4  = (const float*)d_in[17];
    const float* b4  = (const float*)d_in[18];
    const float* g4  = (const float*)d_in[19];
    const float* be4 = (const float*)d_in[20];
    const float* w5  = (const float*)d_in[21];
    const float* b5  = (const float*)d_in[22];
    const float* g5  = (const float*)d_in[23];
    const float* be5 = (const float*)d_in[24];

    const int N = in_sizes[0] / 128;   // 50000
    const int E = in_sizes[1];         // 1600000
    const int* src = ei;
    const int* dst = ei + E;
    const float invN = 1.0f / (float)N;

    float*  ws    = (float*)d_ws;
    float*  bufA  = ws;                                 // N*128 f32 (tmp CSR, then t1,t2,y3,y5)
    ushort* h16   = (ushort*)(ws + (size_t)N * 128);    // N*128 fp16 (xh then y1h)
    float*  y2    = ws + (size_t)N * 192;               // N*64 f32
    float*  y4    = ws + (size_t)N * 128;               // N*96 f32 (overlaps h16+y2, both dead)
    float*  smallr = ws + (size_t)N * 256;
    float*  sums   = smallr;                            // 10 x 128 (sum_l, sq_l)
    float*  scales = smallr + 1280;
    float*  shifts = smallr + 1920;
    float*  w5p    = smallr + 2560;                     // 96*16
    float*  b5p    = w5p + 1536;
    int*    ibase  = (int*)(ws + (size_t)N * 256 + 8192);
    int*    cnt    = ibase;                             // 50048
    int*    off    = cnt + 50048;                       // 50064 (N+1 used)
    int*    headA  = off + 50064;                       // 512 (NB=391 used)
    int*    bsum   = headA + 512;                       // 64
    int2*   edges  = (int2*)(bsum + 64);                // E (final CSR payload)
    int2*   tmp    = (int2*)bufA;                       // E (coarse-bucketed, dead before aggr)
#define SUM(l)   (sums + (l) * 128)
#define SQ(l)    (sums + (5 + (l)) * 128)
#define SCALE(l) (scales + (l) * 128)
#define SHIFT(l) (shifts + (l) * 128)

    hipMemsetAsync(sums, 0, 1280 * sizeof(float), stream);
    hipMemsetAsync(cnt, 0, (size_t)N * sizeof(int), stream);
    pad_w5<<<7, 256, 0, stream>>>(w5, b5, w5p, b5p);
    cvt_f16<<<2048, 256, 0, stream>>>(x, h16, N * 32);

    // ---- CSR build (reused by both convs)
    const int nb = (N + 1023) / 1024;                   // 49
    const int NB = (N + 127) / 128;                     // 391 coarse buckets
    count_dst<<<2048, 256, 0, stream>>>(dst, cnt, E);
    scan1<<<nb, 1024, 0, stream>>>(cnt, off, bsum, N);
    scan2<<<1, 64, 0, stream>>>(bsum, nb);
    scan3<<<nb, 1024, 0, stream>>>(off, bsum, N, E);
    init_headA<<<(NB + 255) / 256, 256, 0, stream>>>(off, headA, NB);
    fill_coarse<<<2048, 256, 0, stream>>>(src, dst, ea, headA, tmp, E);
    fill_fine<<<NB, 256, 0, stream>>>(tmp, off, edges, N);

    const int gemmGrid = (N + 63) / 64;
    const int aggrGrid = (N + 7) / 8;

    // ---- conv1: t1 = x + sum relu(x[src]+e);  y1 = relu(t1@w1+b1) [fp16] + stats
    gine_aggr<false><<<aggrGrid, 256, 0, stream>>>(h16, x, off, edges, lw, lb, nullptr, nullptr, bufA, N);
    gemm_rs<128, 128, 128, 8, 8, false, false, false, true><<<gemmGrid, dim3(32, 8), 0, stream>>>(
        bufA, nullptr, nullptr, nullptr, nullptr, nullptr, w1, b1, h16, SUM(0), SQ(0), N);
    bn_finalize<128><<<1, 128, 0, stream>>>(SUM(0), SQ(0), g1, be1, SCALE(0), SHIFT(0), invN);

    // ---- conv2: t2 = bn(y1) + sum relu(bn(y1)[src]+e);  y2 = relu(t2@w2+b2) + stats
    gine_aggr<true><<<aggrGrid, 256, 0, stream>>>(h16, nullptr, off, edges, lw, lb, SCALE(0), SHIFT(0), bufA, N);
    gemm_rs<128, 128, 64, 16, 4, false, false, false, false><<<gemmGrid, dim3(16, 16), 0, stream>>>(
        bufA, nullptr, nullptr, nullptr, nullptr, nullptr, w2, b2, y2, SUM(1), SQ(1), N);
    bn_finalize<64><<<1, 128, 0, stream>>>(SUM(1), SQ(1), g2, be2, SCALE(1), SHIFT(1), invN);

    // ---- lin1: y3 = relu(concat(bn(y1), bn(y2)) @ w3 + b3) + stats
    gemm_rs<192, 128, 96, 8, 8, true, true, true, false><<<gemmGrid, dim3(24, 8), 0, stream>>>(
        h16, y2, SCALE(0), SHIFT(0), SCALE(1), SHIFT(1), w3, b3, bufA, SUM(2), SQ(2), N);
    bn_finalize<96><<<1, 128, 0, stream>>>(SUM(2), SQ(2), g3, be3, SCALE(2), SHIFT(2), invN);

    // ---- mlp1 layer 1: y4 = relu(bn(y3) @ w4 + b4) + stats
    gemm_rs<96, 96, 96, 8, 8, false, true, false, false><<<gemmGrid, dim3(24, 8), 0, stream>>>(
        bufA, nullptr, SCALE(2), SHIFT(2), nullptr, nullptr, w4, b4, y4, SUM(3), SQ(3), N);
    bn_finalize<96><<<1, 128, 0, stream>>>(SUM(3), SQ(3), g4, be4, SCALE(3), SHIFT(3), invN);

    // ---- mlp1 layer 2: y5 = relu(bn(y4) @ w5p + b5p) [N,16] + stats
    gemm_rs<96, 96, 16, 64, 1, false, true, false, false><<<gemmGrid, dim3(4, 64), 0, stream>>>(
        y4, nullptr, SCALE(3), SHIFT(3), nullptr, nullptr, w5p, b5p, bufA, SUM(4), SQ(4), N);
    bn_finalize<10><<<1, 128, 0, stream>>>(SUM(4), SQ(4), g5, be5, SCALE(4), SHIFT(4), invN);

    // ---- final BN apply -> out [N,10]
    bn_apply_final<<<1024, 256, 0, stream>>>(bufA, SCALE(4), SHIFT(4), (float*)d_out, N * 10);
#undef SUM
#undef SQ
#undef SCALE
#undef SHIFT
}

// Round 6
// 483.918 us; speedup vs baseline: 2.0778x; 2.0778x over previous
//
#include <hip/hip_runtime.h>
#include <hip/hip_fp16.h>

static constexpr float BN_EPS = 1e-5f;

__device__ __forceinline__ ushort f2h(float f) {
    return __half_as_ushort(__float2half(f));           // RNE
}
__device__ __forceinline__ float2 h2f2(uint u) {
    __half2 h = *reinterpret_cast<__half2*>(&u);
    return __half22float2(h);
}

// ---------------------------------------------------------------------------
// fp32 -> fp16 bulk convert (vectorized, grid-stride)
// ---------------------------------------------------------------------------
__global__ __launch_bounds__(256) void cvt_f16(
    const float* __restrict__ in, ushort* __restrict__ out, int n4)
{
    int i = blockIdx.x * 256 + threadIdx.x;
    const int stride = gridDim.x * 256;
    for (; i < n4; i += stride) {
        const float4 v = ((const float4*)in)[i];
        ushort4 u;
        u.x = f2h(v.x); u.y = f2h(v.y); u.z = f2h(v.z); u.w = f2h(v.w);
        ((ushort4*)out)[i] = u;
    }
}

// ---------------------------------------------------------------------------
// CSR build: radix-style two-pass counting sort by dst, no global atomics in
// the scatter paths.
//   count_dst -> scan -> off[] (per-node)
//   hist_blocks: per-(bucket,block) histogram, bucket-major
//   scan of H  : H[b][k] becomes global base (== off[128b] + prefix)
//   scatter_coarse: LDS-positioned scatter into bucket-grouped tmp
//   fill_fine : per-bucket block, LDS per-node heads -> final CSR order
// ---------------------------------------------------------------------------
__global__ __launch_bounds__(256) void count_dst(
    const int* __restrict__ dst, int* __restrict__ cnt, int E)
{
    int i = blockIdx.x * 256 + threadIdx.x;
    const int stride = gridDim.x * 256;
    for (; i < E; i += stride) atomicAdd(&cnt[dst[i]], 1);
}

__device__ inline int wave_incl_scan(int v, int lane)
{
#pragma unroll
    for (int s = 1; s < 64; s <<= 1) {
        const int t = __shfl_up(v, s, 64);
        if (lane >= s) v += t;
    }
    return v;
}

// phase 1: per-block (1024 elems) exclusive scan + block total (in-place safe)
__global__ __launch_bounds__(1024) void scan1(
    const int* __restrict__ cnt, int* __restrict__ off, int* __restrict__ bsum, int n)
{
    __shared__ int wsum[16];
    const int tid = threadIdx.x, lane = tid & 63, wid = tid >> 6;
    const int i = blockIdx.x * 1024 + tid;
    const int v = (i < n) ? cnt[i] : 0;
    const int incl = wave_incl_scan(v, lane);
    if (lane == 63) wsum[wid] = incl;
    __syncthreads();
    if (wid == 0) {
        int wv = (lane < 16) ? wsum[lane] : 0;
        wv = wave_incl_scan(wv, lane);
        if (lane < 16) wsum[lane] = wv;
    }
    __syncthreads();
    const int excl = (wid > 0 ? wsum[wid - 1] : 0) + incl - v;
    if (i < n) off[i] = excl;
    if (tid == 1023) bsum[blockIdx.x] = wsum[15];
}

// phase 2: scan block totals (any nb) with one wave + sequential carry
__global__ __launch_bounds__(64) void scan2(int* __restrict__ bsum, int nb)
{
    const int lane = threadIdx.x;
    int carry = 0;
    for (int base = 0; base < nb; base += 64) {
        const int idx = base + lane;
        const int v = (idx < nb) ? bsum[idx] : 0;
        const int incl = wave_incl_scan(v, lane);
        if (idx < nb) bsum[idx] = carry + incl - v;
        carry += __shfl(incl, 63, 64);
    }
}

// phase 3: add block offsets, set off[n] = total
__global__ __launch_bounds__(1024) void scan3(
    int* __restrict__ off, const int* __restrict__ bsum, int n, int total)
{
    const int i = blockIdx.x * 1024 + threadIdx.x;
    if (i < n) {
        off[i] += bsum[blockIdx.x];
    } else if (i == n) {
        off[n] = total;
    }
}

// per-(bucket,block) histogram, bucket-major layout H[b*NBLK + blk]
__global__ __launch_bounds__(256) void hist_blocks(
    const int* __restrict__ dst, int* __restrict__ H, int E, int NB, int NBLK)
{
    __shared__ int h[512];
    for (int i = threadIdx.x; i < NB; i += 256) h[i] = 0;
    __syncthreads();
    const int chunk = (E + NBLK - 1) / NBLK;
    const int beg = blockIdx.x * chunk;
    const int end = min(beg + chunk, E);
    for (int i = beg + threadIdx.x; i < end; i += 256)
        atomicAdd(&h[dst[i] >> 7], 1);
    __syncthreads();
    for (int i = threadIdx.x; i < NB; i += 256)
        H[(size_t)i * NBLK + blockIdx.x] = h[i];
}

// deterministic coarse scatter: positions from scanned H, LDS-local heads.
// payload = {src | (dst&127)<<20, ea-bits}
__global__ __launch_bounds__(256) void scatter_coarse(
    const int* __restrict__ src, const int* __restrict__ dst,
    const float* __restrict__ ea, const int* __restrict__ H,
    int2* __restrict__ tmp, int E, int NB, int NBLK)
{
    __shared__ int h[512];
    for (int i = threadIdx.x; i < NB; i += 256)
        h[i] = H[(size_t)i * NBLK + blockIdx.x];
    __syncthreads();
    const int chunk = (E + NBLK - 1) / NBLK;
    const int beg = blockIdx.x * chunk;
    const int end = min(beg + chunk, E);
    for (int i = beg + threadIdx.x; i < end; i += 256) {
        const int d = dst[i];
        const int pos = atomicAdd(&h[d >> 7], 1);
        tmp[pos] = make_int2(src[i] | ((d & 127) << 20), __float_as_int(ea[i]));
    }
}

// Pass B: per-bucket fine scatter with LDS heads.
__global__ __launch_bounds__(256) void fill_fine(
    const int2* __restrict__ tmp, const int* __restrict__ off,
    int2* __restrict__ edges, int N)
{
    __shared__ int headl[128];
    const int base = blockIdx.x * 128;
    const int nn = min(128, N - base);
    const int tid = threadIdx.x;
    if (tid < nn) headl[tid] = off[base + tid];
    __syncthreads();
    const int lo = off[base];
    const int hi = off[min(base + 128, N)];
    for (int i = lo + tid; i < hi; i += 256) {
        const int2 p = tmp[i];
        const int dl = (p.x >> 20) & 127;
        const int pos = atomicAdd(&headl[dl], 1);
        edges[pos] = make_int2(p.x & 0xFFFFF, p.y);
    }
}

// ---------------------------------------------------------------------------
// GINE aggregation (CSR): 32 lanes per node (4 cols/lane), 8 nodes per block,
// software-pipelined fp16 row gather.
// acc[node] = res[node] + sum_p relu(xbn[src_p] + a_p*lw + lb)
// ---------------------------------------------------------------------------
template<bool AFF>
__global__ __launch_bounds__(256) void gine_aggr(
    const ushort* __restrict__ xh, const float* __restrict__ xres,
    const int* __restrict__ off, const int2* __restrict__ edges,
    const float* __restrict__ lw, const float* __restrict__ lb,
    const float* __restrict__ sc, const float* __restrict__ sh,
    float* __restrict__ acc, int N)
{
    const int q = threadIdx.x & 31;                 // column quad: cols 4q..4q+3
    const int node = blockIdx.x * 8 + (threadIdx.x >> 5);
    if (node >= N) return;
    const float4 lw4 = ((const float4*)lw)[q];
    const float4 lb4 = ((const float4*)lb)[q];
    float4 sc4, sh4;
    if constexpr (AFF) {
        sc4 = ((const float4*)sc)[q];
        sh4 = ((const float4*)sh)[q];
    }
    float4 s;
    if constexpr (AFF) {
        const uint2 u = ((const uint2*)(xh + (size_t)node * 128))[q];
        const float2 f0 = h2f2(u.x), f1 = h2f2(u.y);
        s.x = fmaf(f0.x, sc4.x, sh4.x);
        s.y = fmaf(f0.y, sc4.y, sh4.y);
        s.z = fmaf(f1.x, sc4.z, sh4.z);
        s.w = fmaf(f1.y, sc4.w, sh4.w);
    } else {
        s = ((const float4*)(xres + (size_t)node * 128))[q];
    }
    int p = off[node];
    const int pend = off[node + 1];
    if (p < pend) {
        int2 e = edges[p];
        uint2 u = ((const uint2*)(xh + (size_t)e.x * 128))[q];
        for (++p; p < pend; ++p) {
            const int2 en = edges[p];
            const uint2 un = ((const uint2*)(xh + (size_t)en.x * 128))[q];
            const float a = __int_as_float(e.y);
            float2 f0 = h2f2(u.x), f1 = h2f2(u.y);
            if constexpr (AFF) {
                f0.x = fmaf(f0.x, sc4.x, sh4.x); f0.y = fmaf(f0.y, sc4.y, sh4.y);
                f1.x = fmaf(f1.x, sc4.z, sh4.z); f1.y = fmaf(f1.y, sc4.w, sh4.w);
            }
            s.x += fmaxf(fmaf(a, lw4.x, lb4.x) + f0.x, 0.f);
            s.y += fmaxf(fmaf(a, lw4.y, lb4.y) + f0.y, 0.f);
            s.z += fmaxf(fmaf(a, lw4.z, lb4.z) + f1.x, 0.f);
            s.w += fmaxf(fmaf(a, lw4.w, lb4.w) + f1.y, 0.f);
            e = en; u = un;
        }
        const float a = __int_as_float(e.y);
        float2 f0 = h2f2(u.x), f1 = h2f2(u.y);
        if constexpr (AFF) {
            f0.x = fmaf(f0.x, sc4.x, sh4.x); f0.y = fmaf(f0.y, sc4.y, sh4.y);
            f1.x = fmaf(f1.x, sc4.z, sh4.z); f1.y = fmaf(f1.y, sc4.w, sh4.w);
        }
        s.x += fmaxf(fmaf(a, lw4.x, lb4.x) + f0.x, 0.f);
        s.y += fmaxf(fmaf(a, lw4.y, lb4.y) + f0.y, 0.f);
        s.z += fmaxf(fmaf(a, lw4.z, lb4.z) + f1.x, 0.f);
        s.w += fmaxf(fmaf(a, lw4.w, lb4.w) + f1.y, 0.f);
    }
    ((float4*)(acc + (size_t)node * 128))[q] = s;
}

// ---------------------------------------------------------------------------
// Fused GEMM + bias + relu + BN-stats epilogue, optional input BN-affine.
// ---------------------------------------------------------------------------
template<int K, int KS, int M, int BY, int TR, bool A1H, bool AFF1, bool AFF2, bool YH>
__global__ __launch_bounds__((M / 4) * BY) void gemm_rs(
    const void* __restrict__ A1v, const float* __restrict__ A2,
    const float* __restrict__ sc1, const float* __restrict__ sh1,
    const float* __restrict__ sc2, const float* __restrict__ sh2,
    const float* __restrict__ W, const float* __restrict__ bias,
    void* __restrict__ Yv, float* __restrict__ sum, float* __restrict__ sq, int N)
{
    constexpr int BX = M / 4;
    constexpr int NT = BX * BY;
    constexpr int R  = BY * TR;        // 64 rows per block
    constexpr int KC = 32;
    constexpr int AST = R + 4;
    __shared__ float Ws[KC * M];
    __shared__ float As[KC * AST];
    __shared__ float Red[2][BY][M];
    const int tx = threadIdx.x, ty = threadIdx.y;
    const int tid = ty * BX + tx;
    const int row0 = blockIdx.x * R;

    float acc[TR][4];
#pragma unroll
    for (int r = 0; r < TR; ++r) { acc[r][0] = acc[r][1] = acc[r][2] = acc[r][3] = 0.f; }

    for (int kc = 0; kc < K; kc += KC) {
        __syncthreads();
        for (int i = tid; i < KC * M / 4; i += NT)
            ((float4*)Ws)[i] = ((const float4*)(W + (size_t)kc * M))[i];
        for (int i = tid; i < R * KC / 4; i += NT) {
            const int r  = i / (KC / 4);
            const int k4 = i % (KC / 4);
            int row = row0 + r; if (row >= N) row = N - 1;   // clamp (stats/stores guarded)
            const int kg = kc + k4 * 4;
            float4 v;
            bool use2 = false;
            if constexpr (KS < K) use2 = (kg >= KS);
            if (use2) {
                const int kl = kg - KS;
                v = *(const float4*)(A2 + (size_t)row * (K - KS) + kl);
                if constexpr (AFF2) {
                    const float4 c = *(const float4*)(sc2 + kl);
                    const float4 d = *(const float4*)(sh2 + kl);
                    v.x = fmaf(v.x, c.x, d.x); v.y = fmaf(v.y, c.y, d.y);
                    v.z = fmaf(v.z, c.z, d.z); v.w = fmaf(v.w, c.w, d.w);
                }
            } else {
                if constexpr (A1H) {
                    const uint2 u = *(const uint2*)((const ushort*)A1v + (size_t)row * KS + kg);
                    const float2 f0 = h2f2(u.x), f1 = h2f2(u.y);
                    v.x = f0.x; v.y = f0.y; v.z = f1.x; v.w = f1.y;
                } else {
                    v = *(const float4*)((const float*)A1v + (size_t)row * KS + kg);
                }
                if constexpr (AFF1) {
                    const float4 c = *(const float4*)(sc1 + kg);
                    const float4 d = *(const float4*)(sh1 + kg);
                    v.x = fmaf(v.x, c.x, d.x); v.y = fmaf(v.y, c.y, d.y);
                    v.z = fmaf(v.z, c.z, d.z); v.w = fmaf(v.w, c.w, d.w);
                }
            }
            As[(k4 * 4 + 0) * AST + r] = v.x;
            As[(k4 * 4 + 1) * AST + r] = v.y;
            As[(k4 * 4 + 2) * AST + r] = v.z;
            As[(k4 * 4 + 3) * AST + r] = v.w;
        }
        __syncthreads();
#pragma unroll 8
        for (int kk = 0; kk < KC; ++kk) {
            const float4 w4 = *(const float4*)&Ws[kk * M + tx * 4];
            float a[TR];
            if constexpr (TR % 4 == 0) {
#pragma unroll
                for (int q = 0; q < TR / 4; ++q) {
                    const float4 av = *(const float4*)&As[kk * AST + ty * TR + q * 4];
                    a[q * 4 + 0] = av.x; a[q * 4 + 1] = av.y;
                    a[q * 4 + 2] = av.z; a[q * 4 + 3] = av.w;
                }
            } else {
#pragma unroll
                for (int r = 0; r < TR; ++r) a[r] = As[kk * AST + ty * TR + r];
            }
#pragma unroll
            for (int r = 0; r < TR; ++r) {
                acc[r][0] = fmaf(a[r], w4.x, acc[r][0]);
                acc[r][1] = fmaf(a[r], w4.y, acc[r][1]);
                acc[r][2] = fmaf(a[r], w4.z, acc[r][2]);
                acc[r][3] = fmaf(a[r], w4.w, acc[r][3]);
            }
        }
    }
    // epilogue: bias + relu + store + per-block column stats
    const float4 b4 = ((const float4*)bias)[tx];
    float s4[4] = {0.f, 0.f, 0.f, 0.f}, q4[4] = {0.f, 0.f, 0.f, 0.f};
#pragma unroll
    for (int r = 0; r < TR; ++r) {
        const int row = row0 + ty * TR + r;
        if (row < N) {
            const float o0 = fmaxf(acc[r][0] + b4.x, 0.f);
            const float o1 = fmaxf(acc[r][1] + b4.y, 0.f);
            const float o2 = fmaxf(acc[r][2] + b4.z, 0.f);
            const float o3 = fmaxf(acc[r][3] + b4.w, 0.f);
            if constexpr (YH) {
                ushort4 u;
                u.x = f2h(o0); u.y = f2h(o1); u.z = f2h(o2); u.w = f2h(o3);
                ((ushort4*)((ushort*)Yv + (size_t)row * M))[tx] = u;
            } else {
                float4 o; o.x = o0; o.y = o1; o.z = o2; o.w = o3;
                ((float4*)((float*)Yv + (size_t)row * M))[tx] = o;
            }
            s4[0] += o0; q4[0] = fmaf(o0, o0, q4[0]);
            s4[1] += o1; q4[1] = fmaf(o1, o1, q4[1]);
            s4[2] += o2; q4[2] = fmaf(o2, o2, q4[2]);
            s4[3] += o3; q4[3] = fmaf(o3, o3, q4[3]);
        }
    }
#pragma unroll
    for (int j = 0; j < 4; ++j) {
        Red[0][ty][tx * 4 + j] = s4[j];
        Red[1][ty][tx * 4 + j] = q4[j];
    }
    __syncthreads();
    if (tid < M) {
        float S = 0.f, Q = 0.f;
#pragma unroll 4
        for (int t = 0; t < BY; ++t) { S += Red[0][t][tid]; Q += Red[1][t][tid]; }
        unsafeAtomicAdd(&sum[tid], S);
        unsafeAtomicAdd(&sq[tid], Q);
    }
}

template<int M>
__global__ void bn_finalize(const float* __restrict__ sum, const float* __restrict__ sq,
                            const float* __restrict__ g, const float* __restrict__ be,
                            float* __restrict__ scale, float* __restrict__ shift, float invN)
{
    const int i = threadIdx.x;
    if (i < M) {
        const float m = sum[i] * invN;
        const float v = sq[i] * invN - m * m;
        const float sc = g[i] * rsqrtf(v + BN_EPS);
        scale[i] = sc;
        shift[i] = be[i] - m * sc;
    }
}

__global__ __launch_bounds__(256) void bn_apply_final(
    const float* __restrict__ Y16, const float* __restrict__ scale,
    const float* __restrict__ shift, float* __restrict__ out, int total)
{
    for (int i = blockIdx.x * 256 + threadIdx.x; i < total; i += gridDim.x * 256) {
        const int n = i / 10;
        const int c = i - n * 10;
        out[i] = fmaf(Y16[(size_t)n * 16 + c], scale[c], shift[c]);
    }
}

// pad w5 [96,10] -> [96,16], b5 [10] -> [16]
__global__ __launch_bounds__(256) void pad_w5(
    const float* __restrict__ w5, const float* __restrict__ b5,
    float* __restrict__ w5p, float* __restrict__ b5p)
{
    const int i = blockIdx.x * 256 + threadIdx.x;
    if (i < 96 * 16) {
        const int k = i >> 4, c = i & 15;
        w5p[i] = (c < 10) ? w5[k * 10 + c] : 0.f;
    } else if (i < 96 * 16 + 16) {
        const int c = i - 96 * 16;
        b5p[c] = (c < 10) ? b5[c] : 0.f;
    }
}

// ---------------------------------------------------------------------------
extern "C" void kernel_launch(void* const* d_in, const int* in_sizes, int n_in,
                              void* d_out, int out_size, void* d_ws, size_t ws_size,
                              hipStream_t stream)
{
    const float* x   = (const float*)d_in[0];
    const float* ea  = (const float*)d_in[1];
    const int*   ei  = (const int*)d_in[2];
    const float* lw  = (const float*)d_in[3];
    const float* lb  = (const float*)d_in[4];
    const float* w1  = (const float*)d_in[5];
    const float* b1  = (const float*)d_in[6];
    const float* g1  = (const float*)d_in[7];
    const float* be1 = (const float*)d_in[8];
    const float* w2  = (const float*)d_in[9];
    const float* b2  = (const float*)d_in[10];
    const float* g2  = (const float*)d_in[11];
    const float* be2 = (const float*)d_in[12];
    const float* w3  = (const float*)d_in[13];
    const float* b3  = (const float*)d_in[14];
    const float* g3  = (const float*)d_in[15];
    const float* be3 = (const float*)d_in[16];
    const float* w4  = (const float*)d_in[17];
    const float* b4  = (const float*)d_in[18];
    const float* g4  = (const float*)d_in[19];
    const float* be4 = (const float*)d_in[20];
    const float* w5  = (const float*)d_in[21];
    const float* b5  = (const float*)d_in[22];
    const float* g5  = (const float*)d_in[23];
    const float* be5 = (const float*)d_in[24];

    const int N = in_sizes[0] / 128;   // 50000
    const int E = in_sizes[1];         // 1600000
    const int* src = ei;
    const int* dst = ei + E;
    const float invN = 1.0f / (float)N;

    float*  ws    = (float*)d_ws;
    float*  bufA  = ws;                                 // N*128 f32 (tmp CSR, then t1,t2,y3,y5)
    ushort* h16   = (ushort*)(ws + (size_t)N * 128);    // N*128 fp16 (xh then y1h)
    float*  y2    = ws + (size_t)N * 192;               // N*64 f32
    float*  y4    = ws + (size_t)N * 128;               // N*96 f32 (overlaps h16+y2, both dead)
    float*  smallr = ws + (size_t)N * 256;
    float*  sums   = smallr;                            // 10 x 128 (sum_l, sq_l)
    float*  scales = smallr + 1280;
    float*  shifts = smallr + 1920;
    float*  w5p    = smallr + 2560;                     // 96*16
    float*  b5p    = w5p + 1536;
    int*    ibase  = (int*)(ws + (size_t)N * 256 + 8192);
    int*    cnt    = ibase;                             // 50048
    int*    off    = cnt + 50048;                       // 50064 (N+1 used)
    int*    bsum   = off + 50064;                       // 128
    int*    H      = bsum + 128;                        // NB*NBLK + 64 = 100160
    int2*   edges  = (int2*)(H + 100160);               // E (final CSR payload)
    int2*   tmp    = (int2*)bufA;                       // E (coarse-bucketed, dead before aggr)
#define SUM(l)   (sums + (l) * 128)
#define SQ(l)    (sums + (5 + (l)) * 128)
#define SCALE(l) (scales + (l) * 128)
#define SHIFT(l) (shifts + (l) * 128)

    hipMemsetAsync(sums, 0, 1280 * sizeof(float), stream);
    hipMemsetAsync(cnt, 0, (size_t)N * sizeof(int), stream);
    pad_w5<<<7, 256, 0, stream>>>(w5, b5, w5p, b5p);
    cvt_f16<<<2048, 256, 0, stream>>>(x, h16, N * 32);

    // ---- CSR build (reused by both convs)
    const int nb   = (N + 1023) / 1024;                 // 49
    const int NB   = (N + 127) / 128;                   // 391 coarse buckets
    const int NBLK = 256;                               // scatter blocks
    const int nH   = NB * NBLK;                         // 100096
    const int nbH  = (nH + 1023) / 1024;                // 98

    count_dst<<<2048, 256, 0, stream>>>(dst, cnt, E);
    scan1<<<nb, 1024, 0, stream>>>(cnt, off, bsum, N);
    scan2<<<1, 64, 0, stream>>>(bsum, nb);
    scan3<<<nb, 1024, 0, stream>>>(off, bsum, N, E);

    hist_blocks<<<NBLK, 256, 0, stream>>>(dst, H, E, NB, NBLK);
    scan1<<<nbH, 1024, 0, stream>>>(H, H, bsum, nH);
    scan2<<<1, 64, 0, stream>>>(bsum, nbH);
    scan3<<<nbH, 1024, 0, stream>>>(H, bsum, nH, E);
    scatter_coarse<<<NBLK, 256, 0, stream>>>(src, dst, ea, H, tmp, E, NB, NBLK);
    fill_fine<<<NB, 256, 0, stream>>>(tmp, off, edges, N);

    const int gemmGrid = (N + 63) / 64;
    const int aggrGrid = (N + 7) / 8;

    // ---- conv1: t1 = x + sum relu(x[src]+e);  y1 = relu(t1@w1+b1) [fp16] + stats
    gine_aggr<false><<<aggrGrid, 256, 0, stream>>>(h16, x, off, edges, lw, lb, nullptr, nullptr, bufA, N);
    gemm_rs<128, 128, 128, 8, 8, false, false, false, true><<<gemmGrid, dim3(32, 8), 0, stream>>>(
        bufA, nullptr, nullptr, nullptr, nullptr, nullptr, w1, b1, h16, SUM(0), SQ(0), N);
    bn_finalize<128><<<1, 128, 0, stream>>>(SUM(0), SQ(0), g1, be1, SCALE(0), SHIFT(0), invN);

    // ---- conv2: t2 = bn(y1) + sum relu(bn(y1)[src]+e);  y2 = relu(t2@w2+b2) + stats
    gine_aggr<true><<<aggrGrid, 256, 0, stream>>>(h16, nullptr, off, edges, lw, lb, SCALE(0), SHIFT(0), bufA, N);
    gemm_rs<128, 128, 64, 16, 4, false, false, false, false><<<gemmGrid, dim3(16, 16), 0, stream>>>(
        bufA, nullptr, nullptr, nullptr, nullptr, nullptr, w2, b2, y2, SUM(1), SQ(1), N);
    bn_finalize<64><<<1, 128, 0, stream>>>(SUM(1), SQ(1), g2, be2, SCALE(1), SHIFT(1), invN);

    // ---- lin1: y3 = relu(concat(bn(y1), bn(y2)) @ w3 + b3) + stats
    gemm_rs<192, 128, 96, 8, 8, true, true, true, false><<<gemmGrid, dim3(24, 8), 0, stream>>>(
        h16, y2, SCALE(0), SHIFT(0), SCALE(1), SHIFT(1), w3, b3, bufA, SUM(2), SQ(2), N);
    bn_finalize<96><<<1, 128, 0, stream>>>(SUM(2), SQ(2), g3, be3, SCALE(2), SHIFT(2), invN);

    // ---- mlp1 layer 1: y4 = relu(bn(y3) @ w4 + b4) + stats
    gemm_rs<96, 96, 96, 8, 8, false, true, false, false><<<gemmGrid, dim3(24, 8), 0, stream>>>(
        bufA, nullptr, SCALE(2), SHIFT(2), nullptr, nullptr, w4, b4, y4, SUM(3), SQ(3), N);
    bn_finalize<96><<<1, 128, 0, stream>>>(SUM(3), SQ(3), g4, be4, SCALE(3), SHIFT(3), invN);

    // ---- mlp1 layer 2: y5 = relu(bn(y4) @ w5p + b5p) [N,16] + stats
    gemm_rs<96, 96, 16, 64, 1, false, true, false, false><<<gemmGrid, dim3(4, 64), 0, stream>>>(
        y4, nullptr, SCALE(3), SHIFT(3), nullptr, nullptr, w5p, b5p, bufA, SUM(4), SQ(4), N);
    bn_finalize<10><<<1, 128, 0, stream>>>(SUM(4), SQ(4), g5, be5, SCALE(4), SHIFT(4), invN);

    // ---- final BN apply -> out [N,10]
    bn_apply_final<<<1024, 256, 0, stream>>>(bufA, SCALE(4), SHIFT(4), (float*)d_out, N * 10);
#undef SUM
#undef SQ
#undef SCALE
#undef SHIFT
}

// Round 7
// 382.865 us; speedup vs baseline: 2.6262x; 1.2639x over previous
//
#include <hip/hip_runtime.h>
#include <hip/hip_fp16.h>

static constexpr float BN_EPS = 1e-5f;

using half8 = __attribute__((ext_vector_type(8))) _Float16;
using f32x4 = __attribute__((ext_vector_type(4))) float;

__device__ __forceinline__ ushort f2h(float f) {
    return __half_as_ushort(__float2half(f));           // RNE
}
__device__ __forceinline__ float2 h2f2(uint u) {
    __half2 h = *reinterpret_cast<__half2*>(&u);
    return __half22float2(h);
}

// ---------------------------------------------------------------------------
// fp32 -> fp16 bulk convert
// ---------------------------------------------------------------------------
__global__ __launch_bounds__(256) void cvt_f16(
    const float* __restrict__ in, ushort* __restrict__ out, int n4)
{
    int i = blockIdx.x * 256 + threadIdx.x;
    const int stride = gridDim.x * 256;
    for (; i < n4; i += stride) {
        const float4 v = ((const float4*)in)[i];
        ushort4 u;
        u.x = f2h(v.x); u.y = f2h(v.y); u.z = f2h(v.z); u.w = f2h(v.w);
        ((ushort4*)out)[i] = u;
    }
}

// ---------------------------------------------------------------------------
// Weight pack: W fp32 [K,M] row-major -> fp16 MFMA fragment order.
// Read side: Wp[((kc*(M/16)+ct)*64 + lane)*8 + j] = W[kc*32 + 8*(lane>>4)+j][ct*16 + (lane&15)]
// ---------------------------------------------------------------------------
__global__ __launch_bounds__(256) void pack_w(
    const float* __restrict__ W, ushort* __restrict__ dst, int K, int M)
{
    const int tid = blockIdx.x * 256 + threadIdx.x;
    if (tid >= K * M) return;
    const int k = tid / M, c = tid % M;
    const int kc = k >> 5, kk = k & 31, ct = c >> 4;
    const int lane = (c & 15) | ((kk >> 3) << 4);
    const int j = kk & 7;
    dst[((size_t)(kc * (M / 16) + ct) * 64 + lane) * 8 + j] = f2h(W[tid]);
}

// ---------------------------------------------------------------------------
// CSR build: radix-style two-pass counting sort by dst, no global atomics.
// ---------------------------------------------------------------------------
__device__ inline int wave_incl_scan(int v, int lane)
{
#pragma unroll
    for (int s = 1; s < 64; s <<= 1) {
        const int t = __shfl_up(v, s, 64);
        if (lane >= s) v += t;
    }
    return v;
}

// per-block (1024 elems) exclusive scan + block total (in-place safe)
__global__ __launch_bounds__(1024) void scan1(
    const int* __restrict__ cnt, int* __restrict__ off, int* __restrict__ bsum, int n)
{
    __shared__ int wsum[16];
    const int tid = threadIdx.x, lane = tid & 63, wid = tid >> 6;
    const int i = blockIdx.x * 1024 + tid;
    const int v = (i < n) ? cnt[i] : 0;
    const int incl = wave_incl_scan(v, lane);
    if (lane == 63) wsum[wid] = incl;
    __syncthreads();
    if (wid == 0) {
        int wv = (lane < 16) ? wsum[lane] : 0;
        wv = wave_incl_scan(wv, lane);
        if (lane < 16) wsum[lane] = wv;
    }
    __syncthreads();
    const int excl = (wid > 0 ? wsum[wid - 1] : 0) + incl - v;
    if (i < n) off[i] = excl;
    if (tid == 1023) bsum[blockIdx.x] = wsum[15];
}

// scan block totals (any nb) with one wave + sequential carry
__global__ __launch_bounds__(64) void scan2(int* __restrict__ bsum, int nb)
{
    const int lane = threadIdx.x;
    int carry = 0;
    for (int base = 0; base < nb; base += 64) {
        const int idx = base + lane;
        const int v = (idx < nb) ? bsum[idx] : 0;
        const int incl = wave_incl_scan(v, lane);
        if (idx < nb) bsum[idx] = carry + incl - v;
        carry += __shfl(incl, 63, 64);
    }
}

// add block offsets
__global__ __launch_bounds__(1024) void scan3(
    int* __restrict__ off, const int* __restrict__ bsum, int n)
{
    const int i = blockIdx.x * 1024 + threadIdx.x;
    if (i < n) off[i] += bsum[blockIdx.x];
}

// per-(bucket,block) histogram, bucket-major layout H[b*NBLK + blk]
__global__ __launch_bounds__(256) void hist_blocks(
    const int* __restrict__ dst, int* __restrict__ H, int E, int NB, int NBLK)
{
    __shared__ int h[512];
    for (int i = threadIdx.x; i < NB; i += 256) h[i] = 0;
    __syncthreads();
    const int chunk = (E + NBLK - 1) / NBLK;
    const int beg = blockIdx.x * chunk;
    const int end = min(beg + chunk, E);
    for (int i = beg + threadIdx.x; i < end; i += 256)
        atomicAdd(&h[dst[i] >> 7], 1);
    __syncthreads();
    for (int i = threadIdx.x; i < NB; i += 256)
        H[(size_t)i * NBLK + blockIdx.x] = h[i];
}

// deterministic coarse scatter: positions from scanned H, LDS-local heads.
// payload = {src | (dst&127)<<20, ea-bits}
__global__ __launch_bounds__(256) void scatter_coarse(
    const int* __restrict__ src, const int* __restrict__ dst,
    const float* __restrict__ ea, const int* __restrict__ H,
    int2* __restrict__ tmp, int E, int NB, int NBLK)
{
    __shared__ int h[512];
    for (int i = threadIdx.x; i < NB; i += 256)
        h[i] = H[(size_t)i * NBLK + blockIdx.x];
    __syncthreads();
    const int chunk = (E + NBLK - 1) / NBLK;
    const int beg = blockIdx.x * chunk;
    const int end = min(beg + chunk, E);
    for (int i = beg + threadIdx.x; i < end; i += 256) {
        const int d = dst[i];
        const int pos = atomicAdd(&h[d >> 7], 1);
        tmp[pos] = make_int2(src[i] | ((d & 127) << 20), __float_as_int(ea[i]));
    }
}

// per-bucket fine scatter; derives per-node off from bucket-local histogram.
__global__ __launch_bounds__(256) void fill_fine2(
    const int2* __restrict__ tmp, const int* __restrict__ H,
    int* __restrict__ off, int2* __restrict__ edges, int N, int E, int NBLK)
{
    __shared__ int cnt[128];
    __shared__ int wtot;
    const int b = blockIdx.x;
    const int base = b * 128;
    const int tid = threadIdx.x;
    const int lo = H[(size_t)b * NBLK];
    const int hi = (b + 1 < (int)gridDim.x) ? H[(size_t)(b + 1) * NBLK] : E;
    if (tid < 128) cnt[tid] = 0;
    __syncthreads();
    for (int i = lo + tid; i < hi; i += 256)
        atomicAdd(&cnt[(tmp[i].x >> 20) & 127], 1);
    __syncthreads();
    int excl = 0;
    if (tid < 128) {
        const int v = cnt[tid];
        const int incl = wave_incl_scan(v, tid & 63);
        if (tid == 63) wtot = incl;
        excl = incl - v;
    }
    __syncthreads();
    if (tid >= 64 && tid < 128) excl += wtot;
    if (tid < 128) {
        const int o = lo + excl;
        if (base + tid < N) off[base + tid] = o;
        cnt[tid] = o;                         // reuse as heads
    }
    if (b == 0 && tid == 0) off[N] = E;
    __syncthreads();
    for (int i = lo + tid; i < hi; i += 256) {
        const int2 p = tmp[i];
        const int dl = (p.x >> 20) & 127;
        const int pos = atomicAdd(&cnt[dl], 1);
        edges[pos] = make_int2(p.x & 0xFFFFF, p.y);
    }
}

// ---------------------------------------------------------------------------
// GINE aggregation (CSR): 32 lanes/node (4 cols/lane), fp16 in / fp16 out.
// outh[node] = fp16( xh[node] + sum_p relu(xh[src_p] + a_p*lw + lb) )
// ---------------------------------------------------------------------------
__global__ __launch_bounds__(256) void gine_aggr(
    const ushort* __restrict__ xh, const int* __restrict__ off,
    const int2* __restrict__ edges, const float* __restrict__ lw,
    const float* __restrict__ lb, ushort* __restrict__ outh, int N)
{
    const int q = threadIdx.x & 31;                 // column quad: cols 4q..4q+3
    const int node = blockIdx.x * 8 + (threadIdx.x >> 5);
    if (node >= N) return;
    const float4 lw4 = ((const float4*)lw)[q];
    const float4 lb4 = ((const float4*)lb)[q];
    float4 s;
    {
        const uint2 u = ((const uint2*)(xh + (size_t)node * 128))[q];
        const float2 f0 = h2f2(u.x), f1 = h2f2(u.y);
        s.x = f0.x; s.y = f0.y; s.z = f1.x; s.w = f1.y;
    }
    int p = off[node];
    const int pend = off[node + 1];
    if (p < pend) {
        int2 e = edges[p];
        uint2 u = ((const uint2*)(xh + (size_t)e.x * 128))[q];
        for (++p; p < pend; ++p) {
            const int2 en = edges[p];
            const uint2 un = ((const uint2*)(xh + (size_t)en.x * 128))[q];
            const float a = __int_as_float(e.y);
            const float2 f0 = h2f2(u.x), f1 = h2f2(u.y);
            s.x += fmaxf(fmaf(a, lw4.x, lb4.x) + f0.x, 0.f);
            s.y += fmaxf(fmaf(a, lw4.y, lb4.y) + f0.y, 0.f);
            s.z += fmaxf(fmaf(a, lw4.z, lb4.z) + f1.x, 0.f);
            s.w += fmaxf(fmaf(a, lw4.w, lb4.w) + f1.y, 0.f);
            e = en; u = un;
        }
        const float a = __int_as_float(e.y);
        const float2 f0 = h2f2(u.x), f1 = h2f2(u.y);
        s.x += fmaxf(fmaf(a, lw4.x, lb4.x) + f0.x, 0.f);
        s.y += fmaxf(fmaf(a, lw4.y, lb4.y) + f0.y, 0.f);
        s.z += fmaxf(fmaf(a, lw4.z, lb4.z) + f1.x, 0.f);
        s.w += fmaxf(fmaf(a, lw4.w, lb4.w) + f1.y, 0.f);
    }
    ushort4 o;
    o.x = f2h(s.x); o.y = f2h(s.y); o.z = f2h(s.z); o.w = f2h(s.w);
    ((ushort4*)(outh + (size_t)node * 128))[q] = o;
}

// ---------------------------------------------------------------------------
// MFMA fp16 GEMM + bias + relu + BN-stats epilogue.
// Y[n,m] = relu(sum_k A[n,k] W[k,m] + b[m]); A fp16 row-major (split at KS),
// W packed fragments, Y fp16 (YH) or fp32. 4 waves x 16 rows = 64 rows/block.
// Fragment layouts (m89/m91-verified): A: row=lane&15, k=8*(lane>>4)+j;
// B: col=lane&15, same k; D: col=lane&15, row=4*(lane>>4)+reg.
// ---------------------------------------------------------------------------
template<int K, int KS, int M, bool YH>
__global__ __launch_bounds__(256) void gemm_mfma(
    const ushort* __restrict__ A1, const ushort* __restrict__ A2,
    const ushort* __restrict__ Wp, const float* __restrict__ bias,
    void* __restrict__ Yv, float* __restrict__ sum, float* __restrict__ sq, int N)
{
    constexpr int NCT = M / 16;
    constexpr int NKC = K / 32;
    __shared__ float redS[4][M];
    __shared__ float redQ[4][M];
    const int tid = threadIdx.x;
    const int w = tid >> 6, l = tid & 63;
    const int col = l & 15, kg = l >> 4;
    const int rowA = blockIdx.x * 64 + w * 16 + col;
    const int rA = (rowA < N) ? rowA : (N - 1);
    f32x4 acc[NCT];
#pragma unroll
    for (int ct = 0; ct < NCT; ++ct) acc[ct] = f32x4{0.f, 0.f, 0.f, 0.f};
#pragma unroll
    for (int kc = 0; kc < NKC; ++kc) {
        const int kbase = kc * 32 + kg * 8;
        half8 a;
        if constexpr (KS < K) {
            if (kbase >= KS) a = *(const half8*)(A2 + (size_t)rA * (K - KS) + (kbase - KS));
            else             a = *(const half8*)(A1 + (size_t)rA * KS + kbase);
        } else {
            a = *(const half8*)(A1 + (size_t)rA * K + kbase);
        }
#pragma unroll
        for (int ct = 0; ct < NCT; ++ct) {
            const half8 wf = *(const half8*)(Wp + ((size_t)(kc * NCT + ct) * 64 + l) * 8);
            acc[ct] = __builtin_amdgcn_mfma_f32_16x16x32_f16(a, wf, acc[ct], 0, 0, 0);
        }
    }
    const int row0 = blockIdx.x * 64 + w * 16 + 4 * kg;
#pragma unroll
    for (int ct = 0; ct < NCT; ++ct) {
        const float bs = bias[ct * 16 + col];
        float sS = 0.f, sQ = 0.f;
#pragma unroll
        for (int r = 0; r < 4; ++r) {
            const int ro = row0 + r;
            if (ro < N) {
                const float o = fmaxf(acc[ct][r] + bs, 0.f);
                if constexpr (YH) ((ushort*)Yv)[(size_t)ro * M + ct * 16 + col] = f2h(o);
                else              ((float*)Yv)[(size_t)ro * M + ct * 16 + col] = o;
                sS += o; sQ = fmaf(o, o, sQ);
            }
        }
        sS += __shfl_xor(sS, 16, 64); sQ += __shfl_xor(sQ, 16, 64);
        sS += __shfl_xor(sS, 32, 64); sQ += __shfl_xor(sQ, 32, 64);
        if (l < 16) { redS[w][ct * 16 + col] = sS; redQ[w][ct * 16 + col] = sQ; }
    }
    __syncthreads();
    for (int i = tid; i < M; i += 256) {
        const float S = redS[0][i] + redS[1][i] + redS[2][i] + redS[3][i];
        const float Q = redQ[0][i] + redQ[1][i] + redQ[2][i] + redQ[3][i];
        unsafeAtomicAdd(&sum[i], S);
        unsafeAtomicAdd(&sq[i], Q);
    }
}

template<int M>
__global__ void bn_finalize(const float* __restrict__ sum, const float* __restrict__ sq,
                            const float* __restrict__ g, const float* __restrict__ be,
                            float* __restrict__ scale, float* __restrict__ shift, float invN)
{
    const int i = threadIdx.x;
    if (i < M) {
        const float m = sum[i] * invN;
        const float v = sq[i] * invN - m * m;
        const float sc = g[i] * rsqrtf(v + BN_EPS);
        scale[i] = sc;
        shift[i] = be[i] - m * sc;
    }
}

// fp16 BN apply: out = fp16(sc*in + sh), 8 halves/thread
template<int M>
__global__ __launch_bounds__(256) void bn_h16(
    const ushort* __restrict__ in, const float* __restrict__ sc,
    const float* __restrict__ sh, ushort* __restrict__ out, int n8)
{
    int i = blockIdx.x * 256 + threadIdx.x;
    const int stride = gridDim.x * 256;
    for (; i < n8; i += stride) {
        const int c8 = i % (M / 8);
        const uint4 u = ((const uint4*)in)[i];
        const float4 c0 = ((const float4*)sc)[c8 * 2];
        const float4 c1 = ((const float4*)sc)[c8 * 2 + 1];
        const float4 d0 = ((const float4*)sh)[c8 * 2];
        const float4 d1 = ((const float4*)sh)[c8 * 2 + 1];
        float2 f;
        ushort4 o0, o1;
        f = h2f2(u.x); o0.x = f2h(fmaf(f.x, c0.x, d0.x)); o0.y = f2h(fmaf(f.y, c0.y, d0.y));
        f = h2f2(u.y); o0.z = f2h(fmaf(f.x, c0.z, d0.z)); o0.w = f2h(fmaf(f.y, c0.w, d0.w));
        f = h2f2(u.z); o1.x = f2h(fmaf(f.x, c1.x, d1.x)); o1.y = f2h(fmaf(f.y, c1.y, d1.y));
        f = h2f2(u.w); o1.z = f2h(fmaf(f.x, c1.z, d1.z)); o1.w = f2h(fmaf(f.y, c1.w, d1.w));
        ((ushort4*)out)[i * 2]     = o0;
        ((ushort4*)out)[i * 2 + 1] = o1;
    }
}

__global__ __launch_bounds__(256) void bn_apply_final(
    const float* __restrict__ Y16, const float* __restrict__ scale,
    const float* __restrict__ shift, float* __restrict__ out, int total)
{
    for (int i = blockIdx.x * 256 + threadIdx.x; i < total; i += gridDim.x * 256) {
        const int n = i / 10;
        const int c = i - n * 10;
        out[i] = fmaf(Y16[(size_t)n * 16 + c], scale[c], shift[c]);
    }
}

// pad w5 [96,10] -> [96,16], b5 [10] -> [16]
__global__ __launch_bounds__(256) void pad_w5(
    const float* __restrict__ w5, const float* __restrict__ b5,
    float* __restrict__ w5p, float* __restrict__ b5p)
{
    const int i = blockIdx.x * 256 + threadIdx.x;
    if (i < 96 * 16) {
        const int k = i >> 4, c = i & 15;
        w5p[i] = (c < 10) ? w5[k * 10 + c] : 0.f;
    } else if (i < 96 * 16 + 16) {
        const int c = i - 96 * 16;
        b5p[c] = (c < 10) ? b5[c] : 0.f;
    }
}

// ---------------------------------------------------------------------------
extern "C" void kernel_launch(void* const* d_in, const int* in_sizes, int n_in,
                              void* d_out, int out_size, void* d_ws, size_t ws_size,
                              hipStream_t stream)
{
    const float* x   = (const float*)d_in[0];
    const float* ea  = (const float*)d_in[1];
    const int*   ei  = (const int*)d_in[2];
    const float* lw  = (const float*)d_in[3];
    const float* lb  = (const float*)d_in[4];
    const float* w1  = (const float*)d_in[5];
    const float* b1  = (const float*)d_in[6];
    const float* g1  = (const float*)d_in[7];
    const float* be1 = (const float*)d_in[8];
    const float* w2  = (const float*)d_in[9];
    const float* b2  = (const float*)d_in[10];
    const float* g2  = (const float*)d_in[11];
    const float* be2 = (const float*)d_in[12];
    const float* w3  = (const float*)d_in[13];
    const float* b3  = (const float*)d_in[14];
    const float* g3  = (const float*)d_in[15];
    const float* be3 = (const float*)d_in[16];
    const float* w4  = (const float*)d_in[17];
    const float* b4  = (const float*)d_in[18];
    const float* g4  = (const float*)d_in[19];
    const float* be4 = (const float*)d_in[20];
    const float* w5  = (const float*)d_in[21];
    const float* b5  = (const float*)d_in[22];
    const float* g5  = (const float*)d_in[23];
    const float* be5 = (const float*)d_in[24];

    const int N = in_sizes[0] / 128;   // 50000
    const int E = in_sizes[1];         // 1600000
    const int* src = ei;
    const int* dst = ei + E;
    const float invN = 1.0f / (float)N;

    float* ws = (float*)d_ws;
    // fp16 pools (sizes in float units)
    ushort* P1 = (ushort*)ws;                           // N*128 h: xh -> y1h -> t2h -> y3h -> y4h
    ushort* P2 = (ushort*)(ws + (size_t)N * 64);        // N*128 h: t1h -> x1h -> x3h -> x4h
    ushort* P3 = (ushort*)(ws + (size_t)N * 128);       // N*64 h:  y2h
    ushort* P4 = (ushort*)(ws + (size_t)N * 160);       // N*64 h:  x2h
    float*  y5 = ws + (size_t)N * 192;                  // N*16 f32
    float*  smallr = ws + (size_t)N * 208;
    float*  sums   = smallr;                            // 10 x 128
    float*  scales = smallr + 1280;                     // 5 x 128
    float*  shifts = smallr + 1920;
    float*  w5p    = smallr + 2560;                     // 96*16 f32
    float*  b5p    = w5p + 1536;                        // 16
    ushort* Wp     = (ushort*)(ws + (size_t)N * 208 + 4224);  // 53760 halves
    ushort* pw1 = Wp, *pw2 = Wp + 16384, *pw3 = Wp + 24576, *pw4 = Wp + 43008, *pw5 = Wp + 52224;
    int*    ibase = (int*)(ws + (size_t)N * 208 + 4224 + 26880);
    int*    H     = ibase;                              // NB*NBLK (+pad) = 100160
    int*    bsum  = H + 100160;                         // 128
    int2*   tmp   = (int2*)(bsum + 128);                // E
    int2*   edges = tmp + E;                            // E
    int*    off   = (int*)(edges + E);                  // N+1
#define SUM(l)   (sums + (l) * 128)
#define SQ(l)    (sums + (5 + (l)) * 128)
#define SCALE(l) (scales + (l) * 128)
#define SHIFT(l) (shifts + (l) * 128)

    hipMemsetAsync(sums, 0, 1280 * sizeof(float), stream);
    pad_w5<<<7, 256, 0, stream>>>(w5, b5, w5p, b5p);
    pack_w<<<(128 * 128 + 255) / 256, 256, 0, stream>>>(w1, pw1, 128, 128);
    pack_w<<<(128 * 64 + 255) / 256, 256, 0, stream>>>(w2, pw2, 128, 64);
    pack_w<<<(192 * 96 + 255) / 256, 256, 0, stream>>>(w3, pw3, 192, 96);
    pack_w<<<(96 * 96 + 255) / 256, 256, 0, stream>>>(w4, pw4, 96, 96);
    pack_w<<<(96 * 16 + 255) / 256, 256, 0, stream>>>(w5p, pw5, 96, 16);
    cvt_f16<<<2048, 256, 0, stream>>>(x, P1, N * 32);   // xh

    // ---- CSR build (reused by both convs)
    const int NB   = (N + 127) / 128;                   // 391 coarse buckets
    const int NBLK = 256;
    const int nH   = NB * NBLK;                         // 100096
    const int nbH  = (nH + 1023) / 1024;                // 98
    hist_blocks<<<NBLK, 256, 0, stream>>>(dst, H, E, NB, NBLK);
    scan1<<<nbH, 1024, 0, stream>>>(H, H, bsum, nH);
    scan2<<<1, 64, 0, stream>>>(bsum, nbH);
    scan3<<<nbH, 1024, 0, stream>>>(H, bsum, nH);
    scatter_coarse<<<NBLK, 256, 0, stream>>>(src, dst, ea, H, tmp, E, NB, NBLK);
    fill_fine2<<<NB, 256, 0, stream>>>(tmp, H, off, edges, N, E, NBLK);

    const int gemmGrid = (N + 63) / 64;                 // 782
    const int aggrGrid = (N + 7) / 8;

    // ---- conv1: t1 = x + sum relu(x[src]+e);  y1 = relu(t1@w1+b1) + stats
    gine_aggr<<<aggrGrid, 256, 0, stream>>>(P1, off, edges, lw, lb, P2, N);          // t1h -> P2
    gemm_mfma<128, 128, 128, true><<<gemmGrid, 256, 0, stream>>>(
        P2, nullptr, pw1, b1, P1, SUM(0), SQ(0), N);                                  // y1h -> P1
    bn_finalize<128><<<1, 128, 0, stream>>>(SUM(0), SQ(0), g1, be1, SCALE(0), SHIFT(0), invN);
    bn_h16<128><<<2048, 256, 0, stream>>>(P1, SCALE(0), SHIFT(0), P2, N * 16);        // x1h -> P2

    // ---- conv2
    gine_aggr<<<aggrGrid, 256, 0, stream>>>(P2, off, edges, lw, lb, P1, N);          // t2h -> P1
    gemm_mfma<128, 128, 64, true><<<gemmGrid, 256, 0, stream>>>(
        P1, nullptr, pw2, b2, P3, SUM(1), SQ(1), N);                                  // y2h -> P3
    bn_finalize<64><<<1, 128, 0, stream>>>(SUM(1), SQ(1), g2, be2, SCALE(1), SHIFT(1), invN);
    bn_h16<64><<<2048, 256, 0, stream>>>(P3, SCALE(1), SHIFT(1), P4, N * 8);          // x2h -> P4

    // ---- lin1: y3 = relu(concat(x1,x2) @ w3 + b3) + stats (K split 128|64)
    gemm_mfma<192, 128, 96, true><<<gemmGrid, 256, 0, stream>>>(
        P2, P4, pw3, b3, P1, SUM(2), SQ(2), N);                                       // y3h -> P1
    bn_finalize<96><<<1, 128, 0, stream>>>(SUM(2), SQ(2), g3, be3, SCALE(2), SHIFT(2), invN);
    bn_h16<96><<<2048, 256, 0, stream>>>(P1, SCALE(2), SHIFT(2), P2, N * 12);         // x3h -> P2

    // ---- mlp1 layer 1
    gemm_mfma<96, 96, 96, true><<<gemmGrid, 256, 0, stream>>>(
        P2, nullptr, pw4, b4, P1, SUM(3), SQ(3), N);                                  // y4h -> P1
    bn_finalize<96><<<1, 128, 0, stream>>>(SUM(3), SQ(3), g4, be4, SCALE(3), SHIFT(3), invN);
    bn_h16<96><<<2048, 256, 0, stream>>>(P1, SCALE(3), SHIFT(3), P2, N * 12);         // x4h -> P2

    // ---- mlp1 layer 2: y5 = relu(x4 @ w5p + b5p) [N,16] f32 + stats
    gemm_mfma<96, 96, 16, false><<<gemmGrid, 256, 0, stream>>>(
        P2, nullptr, pw5, b5p, y5, SUM(4), SQ(4), N);
    bn_finalize<10><<<1, 128, 0, stream>>>(SUM(4), SQ(4), g5, be5, SCALE(4), SHIFT(4), invN);

    // ---- final BN apply -> out [N,10]
    bn_apply_final<<<1024, 256, 0, stream>>>(y5, SCALE(4), SHIFT(4), (float*)d_out, N * 10);
#undef SUM
#undef SQ
#undef SCALE
#undef SHIFT
}